// Round 2
// 1084.348 us; speedup vs baseline: 1.1746x; 1.1746x over previous
//
#include <hip/hip_runtime.h>
#include <stdint.h>

#define N_TOK 8192
#define C_DIM 1024
#define H_DIM 4096

typedef __bf16 bf16x8 __attribute__((ext_vector_type(8)));
typedef float floatx4 __attribute__((ext_vector_type(4)));

__device__ __forceinline__ short f2b(float f) {
    unsigned u = __float_as_uint(f);
    unsigned r = (u + 0x7FFFu + ((u >> 16) & 1u)) >> 16;
    return (short)(r & 0xFFFFu);
}

// gelu(x) = x * sigmoid(2c(x+0.044715x^3)); exp2 + v_rcp (no IEEE divide).
__device__ __forceinline__ float gelu_fast(float x) {
    const float a1 = -2.302114597830384f;    // -2*0.7978845608*1.4426950409
    const float a3 = -0.10294096656926834f;  // a1*0.044715
    float x2 = x * x;
    float m = x * (a1 + a3 * x2);
    float e = __builtin_amdgcn_exp2f(m);
    return x * __builtin_amdgcn_rcpf(1.0f + e);
}

// async global->LDS, 16B per lane; lds dest is wave-uniform base + lane*16
__device__ __forceinline__ void gl_lds16(const short* g, short* l) {
    __builtin_amdgcn_global_load_lds(
        (const __attribute__((address_space(1))) unsigned int*)g,
        (__attribute__((address_space(3))) unsigned int*)l, 16, 0, 0);
}

// ---------------- cast x (fp32 -> bf16 bits) ----------------
__global__ void cast_x_k(const float* __restrict__ in, short* __restrict__ out) {
    int i = (blockIdx.x * 256 + threadIdx.x) * 4;
    float4 v = *(const float4*)(in + i);
    short4 o;
    o.x = f2b(v.x); o.y = f2b(v.y); o.z = f2b(v.z); o.w = f2b(v.w);
    *(short4*)(out + i) = o;
}

// ------------- transpose + cast weights: W[K,N] fp32 -> WT[N,K] bf16 -------------
__global__ void transpose_cast_k(const float* __restrict__ W, short* __restrict__ WT,
                                 int K, int N) {
    __shared__ float tile[32][33];
    size_t moff = (size_t)blockIdx.z * (size_t)K * (size_t)N;
    int n0 = blockIdx.x * 32, k0 = blockIdx.y * 32;
    int tx = threadIdx.x, ty = threadIdx.y;  // (32, 8)
#pragma unroll
    for (int j = 0; j < 32; j += 8)
        tile[ty + j][tx] = W[moff + (size_t)(k0 + ty + j) * N + n0 + tx];
    __syncthreads();
#pragma unroll
    for (int j = 0; j < 32; j += 8)
        WT[moff + (size_t)(n0 + ty + j) * K + k0 + tx] = f2b(tile[tx][ty + j]);
}

// ---------------- init: shared expert = expert 8, identity list, gate 1 ----------------
__global__ void init_shared_k(int* __restrict__ tok_list, float* __restrict__ gate_list,
                              int* __restrict__ counts) {
    int i = blockIdx.x * 256 + threadIdx.x;
    tok_list[8 * N_TOK + i] = i;
    gate_list[8 * N_TOK + i] = 1.0f;
    if (i == 0) counts[8] = N_TOK;
}

// ---------------- router: logits, softmax, top2, expert lists ----------------
__global__ void router_k(const float* __restrict__ x, const float* __restrict__ Wr,
                         int* __restrict__ counts, int* __restrict__ tok_list,
                         float* __restrict__ gate_list, int* __restrict__ ent) {
    int token = blockIdx.x * 4 + (threadIdx.x >> 6);
    int lane = threadIdx.x & 63;
    const float* xr = x + (size_t)token * C_DIM;
    float p[8];
#pragma unroll
    for (int e = 0; e < 8; ++e) p[e] = 0.f;
    for (int jj = 0; jj < 4; ++jj) {
        int c = (jj * 64 + lane) * 4;
        float4 xv = *(const float4*)(xr + c);
        const float* w = Wr + (size_t)c * 8;
        float xs[4] = {xv.x, xv.y, xv.z, xv.w};
#pragma unroll
        for (int q = 0; q < 4; ++q)
#pragma unroll
            for (int e = 0; e < 8; ++e) p[e] += xs[q] * w[q * 8 + e];
    }
#pragma unroll
    for (int e = 0; e < 8; ++e)
#pragma unroll
        for (int off = 32; off > 0; off >>= 1) p[e] += __shfl_down(p[e], off);
    if (lane == 0) {
        float mx = p[0];
#pragma unroll
        for (int e = 1; e < 8; ++e) mx = fmaxf(mx, p[e]);
        float ex[8];
#pragma unroll
        for (int e = 0; e < 8; ++e) ex[e] = __expf(p[e] - mx);
        int i1 = 0;
#pragma unroll
        for (int e = 1; e < 8; ++e) if (ex[e] > ex[i1]) i1 = e;
        int i2 = (i1 == 0) ? 1 : 0;
#pragma unroll
        for (int e = 0; e < 8; ++e) if (e != i1 && ex[e] > ex[i2]) i2 = e;
        float s2 = ex[i1] + ex[i2];
        float g1 = ex[i1] / s2, g2 = ex[i2] / s2;
        int pos1 = atomicAdd(&counts[i1], 1);
        tok_list[i1 * N_TOK + pos1] = token;
        gate_list[i1 * N_TOK + pos1] = g1;
        ent[token * 2] = (i1 << 16) | pos1;
        int pos2 = atomicAdd(&counts[i2], 1);
        tok_list[i2 * N_TOK + pos2] = token;
        gate_list[i2 * N_TOK + pos2] = g2;
        ent[token * 2 + 1] = (i2 << 16) | pos2;
    }
}

__global__ void offsets_k(const int* __restrict__ counts, int* __restrict__ offs) {
    if (threadIdx.x == 0) {
        int a = 0;
        for (int e = 0; e < 9; ++e) { offs[e] = a; a += counts[e]; }
    }
}

// ======================= 256x256 8-phase MoE GEMM =======================
// BM=BN=256, BK=64, 512 threads (8 waves, 2Mx4N), per-wave C = 128x64.
// Static LDS: 2 buffers x (A 32K + B 32K) = 128 KB. Each A/B tile stored as two
// k-half planes [256 rows][32 k] bf16 (16 KB each) so staging order matches
// consumption order (kh0 planes used in phases 0-1, kh1 in phases 2-3).
// Counted vmcnt(4) at phases 1/3 keeps 4 global_load_lds in flight across
// every barrier (T3+T4); XOR-swizzled LDS (T2: pre-swizzled global source +
// swizzled ds_read); setprio around MFMA (T5).
#define SWZ(r) (((r) ^ ((r) >> 2)) & 3)

template <bool STAGE>
__device__ __forceinline__ void tile_body(
    char* cb, char* sb, int wave,
    const short* a0, const short* a1, const short* b0, const short* b1, int ko,
    const int (&aoff)[8], const int (&boff)[4], floatx4 (&acc)[8][4]) {
    bf16x8 afr[4], bfr[4];
    // ---- phase 0: kh0, m 0..3 ----
#pragma unroll
    for (int n = 0; n < 4; ++n) bfr[n] = *(const bf16x8*)(cb + 32768 + boff[n]);
#pragma unroll
    for (int m = 0; m < 4; ++m) afr[m] = *(const bf16x8*)(cb + aoff[m]);
    if (STAGE) {
        gl_lds16(a0 + ko, (short*)(sb + wave * 1024));
        gl_lds16(a1 + ko, (short*)(sb + 8192 + wave * 1024));
    }
    __builtin_amdgcn_s_barrier();
    asm volatile("s_waitcnt lgkmcnt(0)" ::: "memory");
    __builtin_amdgcn_s_setprio(1);
#pragma unroll
    for (int m = 0; m < 4; ++m)
#pragma unroll
        for (int n = 0; n < 4; ++n)
            acc[m][n] = __builtin_amdgcn_mfma_f32_16x16x32_bf16(afr[m], bfr[n], acc[m][n], 0, 0, 0);
    __builtin_amdgcn_s_setprio(0);
    __builtin_amdgcn_s_barrier();
    // ---- phase 1: kh0, m 4..7 ----
#pragma unroll
    for (int m = 0; m < 4; ++m) afr[m] = *(const bf16x8*)(cb + aoff[4 + m]);
    if (STAGE) {
        gl_lds16(b0 + ko, (short*)(sb + 32768 + wave * 1024));
        gl_lds16(b1 + ko, (short*)(sb + 40960 + wave * 1024));
    }
    __builtin_amdgcn_s_barrier();
    asm volatile("s_waitcnt lgkmcnt(0)" ::: "memory");
    __builtin_amdgcn_s_setprio(1);
#pragma unroll
    for (int m = 0; m < 4; ++m)
#pragma unroll
        for (int n = 0; n < 4; ++n)
            acc[4 + m][n] = __builtin_amdgcn_mfma_f32_16x16x32_bf16(afr[m], bfr[n], acc[4 + m][n], 0, 0, 0);
    __builtin_amdgcn_s_setprio(0);
    // kh1 planes of THIS tile (issued 2 phases back) must be done; 4 newest
    // (this tile's kh0 prefetch of t+1) may stay in flight.
    if (STAGE) asm volatile("s_waitcnt vmcnt(4)\n\ts_barrier" ::: "memory");
    else       asm volatile("s_waitcnt vmcnt(0)\n\ts_barrier" ::: "memory");
    // ---- phase 2: kh1, m 0..3 ----
#pragma unroll
    for (int n = 0; n < 4; ++n) bfr[n] = *(const bf16x8*)(cb + 49152 + boff[n]);
#pragma unroll
    for (int m = 0; m < 4; ++m) afr[m] = *(const bf16x8*)(cb + 16384 + aoff[m]);
    if (STAGE) {
        gl_lds16(a0 + ko + 32, (short*)(sb + 16384 + wave * 1024));
        gl_lds16(a1 + ko + 32, (short*)(sb + 24576 + wave * 1024));
    }
    __builtin_amdgcn_s_barrier();
    asm volatile("s_waitcnt lgkmcnt(0)" ::: "memory");
    __builtin_amdgcn_s_setprio(1);
#pragma unroll
    for (int m = 0; m < 4; ++m)
#pragma unroll
        for (int n = 0; n < 4; ++n)
            acc[m][n] = __builtin_amdgcn_mfma_f32_16x16x32_bf16(afr[m], bfr[n], acc[m][n], 0, 0, 0);
    __builtin_amdgcn_s_setprio(0);
    __builtin_amdgcn_s_barrier();
    // ---- phase 3: kh1, m 4..7 ----
#pragma unroll
    for (int m = 0; m < 4; ++m) afr[m] = *(const bf16x8*)(cb + 16384 + aoff[4 + m]);
    if (STAGE) {
        gl_lds16(b0 + ko + 32, (short*)(sb + 49152 + wave * 1024));
        gl_lds16(b1 + ko + 32, (short*)(sb + 57344 + wave * 1024));
    }
    __builtin_amdgcn_s_barrier();
    asm volatile("s_waitcnt lgkmcnt(0)" ::: "memory");
    __builtin_amdgcn_s_setprio(1);
#pragma unroll
    for (int m = 0; m < 4; ++m)
#pragma unroll
        for (int n = 0; n < 4; ++n)
            acc[4 + m][n] = __builtin_amdgcn_mfma_f32_16x16x32_bf16(afr[m], bfr[n], acc[4 + m][n], 0, 0, 0);
    __builtin_amdgcn_s_setprio(0);
    // kh0 planes of t+1 (issued at phases 0/1) must be done before next tile.
    if (STAGE) asm volatile("s_waitcnt vmcnt(4)\n\ts_barrier" ::: "memory");
    else       __builtin_amdgcn_s_barrier();
}

// IS_FC: A rows gathered via tok_list[e], epi = gelu.  else: A rows = off+m, epi = *gate.
template <bool IS_FC>
__global__ __launch_bounds__(512, 2) void gemm_k(
    const short* __restrict__ Abase, const short* __restrict__ Bbase,
    const float* __restrict__ biasbase, short* __restrict__ Out,
    const int* __restrict__ counts, const int* __restrict__ offs,
    const int* __restrict__ tok_base, const float* __restrict__ gate_base,
    int K, int N) {
    __shared__ __align__(16) char sm_b[131072];  // static 128 KB LDS
    const int e = blockIdx.z;
    const int count = counts[e];
    const int mt = blockIdx.y, nt = blockIdx.x;
    if (mt * 256 >= count) return;
    const int off = offs[e];
    const int m0 = mt * 256, n0 = nt * 256;
    const short* Bm = Bbase + (size_t)e * (size_t)K * (size_t)N;
    const float* bias = biasbase + (size_t)e * (size_t)N;
    const int tid = threadIdx.x;
    const int wave = tid >> 6, lane = tid & 63;
    const int wm128 = (wave >> 2) * 128, wn64 = (wave & 3) * 64;
    const int fr = lane & 15, quad = lane >> 4;

    // ---- staging source pointers: thread covers plane rows rs0 (round0) / rs1 (round1)
    const int rs0 = wave * 16 + (lane >> 2), rs1 = 128 + rs0;
    const int ca0 = ((lane & 3) ^ SWZ(rs0)) * 8;
    const int ca1 = ((lane & 3) ^ SWZ(rs1)) * 8;
    int am0 = min(m0 + rs0, count - 1), am1 = min(m0 + rs1, count - 1);
    size_t ga0, ga1;
    if (IS_FC) {
        const int* list = tok_base + e * N_TOK;
        ga0 = (size_t)list[am0];
        ga1 = (size_t)list[am1];
    } else {
        ga0 = (size_t)(off + am0);
        ga1 = (size_t)(off + am1);
    }
    const short* a0 = Abase + ga0 * K + ca0;
    const short* a1 = Abase + ga1 * K + ca1;
    const short* b0 = Bm + (size_t)(n0 + rs0) * K + ca0;
    const short* b1 = Bm + (size_t)(n0 + rs1) * K + ca1;

    // ---- fragment LDS byte offsets (within one 16 KB plane)
    int aoff[8], boff[4];
#pragma unroll
    for (int m = 0; m < 8; ++m) {
        int r = wm128 + m * 16 + fr;
        aoff[m] = r * 64 + ((quad ^ SWZ(r)) << 4);
    }
#pragma unroll
    for (int n = 0; n < 4; ++n) {
        int r = wn64 + n * 16 + fr;
        boff[n] = r * 64 + ((quad ^ SWZ(r)) << 4);
    }

    floatx4 acc[8][4];
#pragma unroll
    for (int i = 0; i < 8; ++i)
#pragma unroll
        for (int j = 0; j < 4; ++j) acc[i][j] = (floatx4){0.f, 0.f, 0.f, 0.f};

    // ---- prologue: stage tile 0 -> buf0 (A-kh0, B-kh0, A-kh1, B-kh1)
    gl_lds16(a0,      (short*)(sm_b +     0 + wave * 1024));
    gl_lds16(a1,      (short*)(sm_b +  8192 + wave * 1024));
    gl_lds16(b0,      (short*)(sm_b + 32768 + wave * 1024));
    gl_lds16(b1,      (short*)(sm_b + 40960 + wave * 1024));
    gl_lds16(a0 + 32, (short*)(sm_b + 16384 + wave * 1024));
    gl_lds16(a1 + 32, (short*)(sm_b + 24576 + wave * 1024));
    gl_lds16(b0 + 32, (short*)(sm_b + 49152 + wave * 1024));
    gl_lds16(b1 + 32, (short*)(sm_b + 57344 + wave * 1024));
    asm volatile("s_waitcnt vmcnt(4)\n\ts_barrier" ::: "memory");  // kh0 planes ready

    const int kIters = K / 64;  // 16 (fc) or 64 (proj) -- both even
    for (int t = 0; t < kIters - 1; ++t) {
        char* cb = sm_b + (t & 1) * 65536;
        char* sb = sm_b + ((t & 1) ^ 1) * 65536;
        tile_body<true>(cb, sb, wave, a0, a1, b0, b1, (t + 1) * 64, aoff, boff, acc);
    }
    tile_body<false>(sm_b + ((kIters - 1) & 1) * 65536, sm_b, wave,
                     a0, a1, b0, b1, 0, aoff, boff, acc);

    // ---- epilogue: per-wave LDS repack (slab 16 x 72 shorts in buf0 -- tail read buf1)
    float bcol[4];
#pragma unroll
    for (int j = 0; j < 4; ++j) bcol[j] = bias[n0 + wn64 + j * 16 + fr];

    short* slab = (short*)sm_b + wave * 1152;
    const int rr = lane >> 2, cc = lane & 3;
    const int srow_m = m0 + wm128 + rr;
    short* sw = slab + quad * 288 + fr;
    const short* srd = slab + rr * 72 + cc * 16;
    const float* gl = gate_base + (IS_FC ? 0 : e * N_TOK);

#pragma unroll
    for (int i = 0; i < 8; ++i) {
        float g4[4];
        if (!IS_FC) {
#pragma unroll
            for (int r = 0; r < 4; ++r)
                g4[r] = gl[min(m0 + wm128 + i * 16 + quad * 4 + r, count - 1)];
        }
#pragma unroll
        for (int j = 0; j < 4; ++j)
#pragma unroll
            for (int r = 0; r < 4; ++r) {
                float v = acc[i][j][r] + bcol[j];
                if (IS_FC) v = gelu_fast(v); else v *= g4[r];
                sw[r * 72 + j * 16] = f2b(v);
            }
        int m = srow_m + i * 16;
        if (m < count) {
            int4 v0 = *(const int4*)srd;
            int4 v1 = *(const int4*)(srd + 8);
            short* orow = Out + (size_t)(off + m) * (size_t)N + n0 + wn64 + cc * 16;
            *(int4*)orow = v0;
            *(int4*)(orow + 8) = v1;
        }
        asm volatile("s_waitcnt lgkmcnt(0)" ::: "memory");  // slab reads done before next i
    }
}

// ---------------- combine: out[t] = shared_row + rout[ent0] + rout[ent1] (bf16 -> f32) ----------------
__global__ void combine_k(float* __restrict__ out, const short* __restrict__ routc,
                          const int* __restrict__ ent, const int* __restrict__ offs) {
    int tid = threadIdx.x;
    int t = blockIdx.x * 2 + (tid >> 7);
    int c = (tid & 127) * 8;
    int p0 = ent[t * 2], p1 = ent[t * 2 + 1];
    size_t r0 = (size_t)(offs[p0 >> 16] + (p0 & 0xFFFF)) * 1024 + c;
    size_t r1 = (size_t)(offs[p1 >> 16] + (p1 & 0xFFFF)) * 1024 + c;
    size_t rs = (size_t)(16384 + t) * 1024 + c;
    int4 va = *(const int4*)(routc + rs);
    int4 vb = *(const int4*)(routc + r0);
    int4 vc = *(const int4*)(routc + r1);
    float o[8];
    const int* pa = (const int*)&va;
    const int* pb = (const int*)&vb;
    const int* pc = (const int*)&vc;
#pragma unroll
    for (int q = 0; q < 4; ++q) {
        unsigned a = pa[q], b = pb[q], cw = pc[q];
        o[2 * q] = __uint_as_float(a << 16) + __uint_as_float(b << 16) + __uint_as_float(cw << 16);
        o[2 * q + 1] = __uint_as_float(a & 0xFFFF0000u) + __uint_as_float(b & 0xFFFF0000u) +
                       __uint_as_float(cw & 0xFFFF0000u);
    }
    float* op = out + (size_t)t * 1024 + c;
    *(float4*)op = (float4){o[0], o[1], o[2], o[3]};
    *(float4*)(op + 4) = (float4){o[4], o[5], o[6], o[7]};
}

extern "C" void kernel_launch(void* const* d_in, const int* in_sizes, int n_in,
                              void* d_out, int out_size, void* d_ws, size_t ws_size,
                              hipStream_t stream) {
    const float* x       = (const float*)d_in[0];
    const float* Wfc_s   = (const float*)d_in[1];
    const float* bfc_s   = (const float*)d_in[2];
    const float* Wproj_s = (const float*)d_in[3];
    const float* bproj_s = (const float*)d_in[4];
    const float* Wr      = (const float*)d_in[5];
    const float* Wfc     = (const float*)d_in[6];
    const float* bfc     = (const float*)d_in[7];
    const float* Wproj   = (const float*)d_in[8];
    const float* bproj   = (const float*)d_in[9];
    float* out = (float*)d_out;

    char* p = (char*)d_ws;
    short* xb      = (short*)p; p += (size_t)N_TOK * C_DIM * 2;              // 16.8 MB
    short* WfcT    = (short*)p; p += (size_t)9 * C_DIM * H_DIM * 2;          // 75.5 MB
    short* WprojT  = (short*)p; p += (size_t)9 * C_DIM * H_DIM * 2;          // 75.5 MB
    float* bfc_all = (float*)p; p += (size_t)9 * H_DIM * 4;                  // 147 KB
    float* bpj_all = (float*)p; p += (size_t)9 * C_DIM * 4;                  // 37 KB
    short* h       = (short*)p; p += (size_t)24576 * H_DIM * 2;              // 201 MB
    short* routc   = (short*)p; p += (size_t)24576 * C_DIM * 2;              // 50 MB
    int*   counts  = (int*)p;   p += 128;
    int*   offs    = (int*)p;   p += 128;
    int*   tok_list  = (int*)p;   p += (size_t)9 * N_TOK * 4;
    float* gate_list = (float*)p; p += (size_t)9 * N_TOK * 4;
    int*   ent     = (int*)p;   p += (size_t)N_TOK * 2 * 4;

    hipMemsetAsync(counts, 0, 64, stream);
    cast_x_k<<<8192, 256, 0, stream>>>(x, xb);
    transpose_cast_k<<<dim3(128, 32, 8), dim3(32, 8), 0, stream>>>(Wfc, WfcT, 1024, 4096);
    transpose_cast_k<<<dim3(128, 32, 1), dim3(32, 8), 0, stream>>>(Wfc_s, WfcT + (size_t)8 * C_DIM * H_DIM, 1024, 4096);
    transpose_cast_k<<<dim3(32, 128, 8), dim3(32, 8), 0, stream>>>(Wproj, WprojT, 4096, 1024);
    transpose_cast_k<<<dim3(32, 128, 1), dim3(32, 8), 0, stream>>>(Wproj_s, WprojT + (size_t)8 * C_DIM * H_DIM, 4096, 1024);
    hipMemcpyAsync(bfc_all, bfc, (size_t)8 * H_DIM * 4, hipMemcpyDeviceToDevice, stream);
    hipMemcpyAsync(bfc_all + 8 * H_DIM, bfc_s, (size_t)H_DIM * 4, hipMemcpyDeviceToDevice, stream);
    hipMemcpyAsync(bpj_all, bproj, (size_t)8 * C_DIM * 4, hipMemcpyDeviceToDevice, stream);
    hipMemcpyAsync(bpj_all + 8 * C_DIM, bproj_s, (size_t)C_DIM * 4, hipMemcpyDeviceToDevice, stream);
    init_shared_k<<<32, 256, 0, stream>>>(tok_list, gate_list, counts);
    router_k<<<2048, 256, 0, stream>>>(x, Wr, counts, tok_list, gate_list, ent);
    offsets_k<<<1, 64, 0, stream>>>(counts, offs);

    // fc: all 9 experts (8 routed + shared), gelu, bf16 h
    gemm_k<true><<<dim3(16, 32, 9), 512, 0, stream>>>(
        xb, WfcT, bfc_all, h, counts, offs, tok_list, gate_list, C_DIM, H_DIM);
    // proj: all 9 experts, gate-scaled (gate=1 for shared), bf16 routc
    gemm_k<false><<<dim3(4, 32, 9), 512, 0, stream>>>(
        h, WprojT, bpj_all, routc, counts, offs, tok_list, gate_list, H_DIM, C_DIM);
    combine_k<<<4096, 256, 0, stream>>>(out, routc, ent, offs);
}